// Round 4
// baseline (313.504 us; speedup 1.0000x reference)
//
#include <hip/hip_runtime.h>
#include <hip/hip_bf16.h>

#define M_DIM 8192
#define N_DIM 4096
#define K_DIM 4096
#define NT (K_DIM / 64)   // 64 K-tiles of BK=64

typedef __bf16 bf16x8 __attribute__((ext_vector_type(8)));
typedef float f32x4 __attribute__((ext_vector_type(4)));
typedef unsigned short ushort8v __attribute__((ext_vector_type(8)));

typedef const __attribute__((address_space(1))) void gv_t;
typedef __attribute__((address_space(3))) void lv_t;

static __device__ __forceinline__ unsigned short f2bf(float f) {
  unsigned u = __builtin_bit_cast(unsigned, f);
  u += 0x7fffu + ((u >> 16) & 1u);
  return (unsigned short)(u >> 16);
}

// ---------------- pre-pass 1: inverse permutation ----------------
__global__ void k_pinv(const int* __restrict__ ci, int* __restrict__ pinv) {
  int k = blockIdx.x * 256 + threadIdx.x;
  if (k < K_DIM) pinv[ci[k]] = k;
}

// ---------------- pre-pass 2: x fp32 -> bf16 ----------------
__global__ void k_cvt(const float* __restrict__ x, unsigned short* __restrict__ xb) {
  const long n4 = (long)M_DIM * K_DIM / 4;
  for (long i = (long)blockIdx.x * 256 + threadIdx.x; i < n4; i += 2048L * 256) {
    float4 v = *(const float4*)(x + i * 4);
    ushort4 o;
    o.x = f2bf(v.x); o.y = f2bf(v.y); o.z = f2bf(v.z); o.w = f2bf(v.w);
    *(ushort4*)(xb + i * 4) = o;
  }
}

// ---------------- pre-pass 3: dequant + permute + transpose ----------------
// w2t[n][c] = (float)w[pinv[c]][n] * scales[pinv[c]>>7][n]  as bf16, [N][K]
__global__ void k_w2t(const int* __restrict__ w, const float* __restrict__ scales,
                      const int* __restrict__ pinv, unsigned short* __restrict__ w2t) {
  __shared__ int tile[64 * 68];
  __shared__ int grp[64];
  __shared__ int krow[64];
  const int n0 = blockIdx.x * 64;
  const int c0 = blockIdx.y * 64;
  const int t = threadIdx.x;
  if (t < 64) {
    int kk = pinv[c0 + t];
    krow[t] = kk;
    grp[t] = kk >> 7;
  }
  __syncthreads();
  {
    const int ci = t >> 2, q = t & 3;
    const int kk = krow[ci];
    const int* src = w + (long)kk * N_DIM + n0 + q * 16;
#pragma unroll
    for (int j = 0; j < 4; ++j) {
      int4 v = *(const int4*)(src + j * 4);
      *(int4*)&tile[ci * 68 + q * 16 + j * 4] = v;
    }
  }
  __syncthreads();
  {
    const int nj = t >> 2, cq = t & 3;
    const int n = n0 + nj;
    unsigned short outv[16];
#pragma unroll
    for (int i = 0; i < 16; ++i) {
      int cii = cq * 16 + i;
      float f = (float)tile[cii * 68 + nj] * scales[grp[cii] * N_DIM + n];
      outv[i] = f2bf(f);
    }
    unsigned short* dst = w2t + (long)n * K_DIM + c0 + cq * 16;
    *(ushort8v*)(dst)     = *(ushort8v*)&outv[0];
    *(ushort8v*)(dst + 8) = *(ushort8v*)&outv[8];
  }
}

// ---------------- main GEMM: 256x256, BK=64, 8 waves, 4-phase reg-pipeline ----------------
// 2 LDS buffers x (A 32K + B 32K) = 128 KiB. Phases (mih,kh): p0(0,0) p1(1,0) p2(0,1) p3(1,1).
// Each phase: ds_read next phase's operands; 16 MFMA on regs read last phase.
// Tile t+1's 8 staging loads all issue at p0(t); vmcnt(0)+barrier at p2-end (2-phase lag,
// queue already drained); barrier at p3-end. 2 barriers / 64-K tile.
__global__ __launch_bounds__(512, 2) void k_gemm(const unsigned short* __restrict__ A,
                                                 const unsigned short* __restrict__ Bt,
                                                 const float* __restrict__ bias,
                                                 float* __restrict__ C) {
  __shared__ __attribute__((aligned(16))) char lds[2 * 65536];   // 128 KiB

  const int bid = blockIdx.x;                  // 512 blocks, %8==0 -> bijective
  const int swz = (bid & 7) * 64 + (bid >> 3);
  const int by = swz >> 4;                     // 0..31
  const int bx = swz & 15;                     // 0..15

  const int tid = threadIdx.x;
  const int l = tid & 63;
  const int w = tid >> 6;
  const int wr = w >> 2;        // 0..1
  const int wc = w & 3;         // 0..3
  const int r4 = l & 15;
  const int kb = (l >> 4) << 4;               // 0,16,32,48 bytes within 64B k-half

  // ---- staging source addresses (pre-swizzled; LDS dest linear) ----
  // load j covers LDS [j*8192,+8192) = rows j*64 + (tid>>3), phys kb = (tid&7)*16
  // logical kb = phys ^ wmask with wmask = ((row&7)<<4) = ((tid>>3)&7)<<4
  const int wmask = ((tid >> 3) & 7) << 4;
  const int kbo = ((tid & 7) * 16) ^ wmask;
  const char* srcA = (const char*)A + (size_t)(by * 256 + (tid >> 3)) * (K_DIM * 2) + kbo;
  const char* srcB = (const char*)Bt + (size_t)(bx * 256 + (tid >> 3)) * (K_DIM * 2) + kbo;
  const int stgoff = tid * 16;

  // ---- LDS fragment read bases: addr = ((row<<7)+kb) ^ ((row&7)<<4) ----
  const int R0A = wr * 128 + r4;
  const int R0B = wc * 64 + r4;
  const int aoff0 = ((R0A << 7) + kb) ^ ((R0A & 7) << 4);   // (mih0, kh0); +8192 for mih1; ^64 for kh1
  const int boff0 = ((R0B << 7) + kb) ^ ((R0B & 7) << 4);

  f32x4 acc[8][4];
  const f32x4 z = {0.f, 0.f, 0.f, 0.f};
#pragma unroll
  for (int mi = 0; mi < 8; ++mi)
#pragma unroll
    for (int ni = 0; ni < 4; ++ni) acc[mi][ni] = z;

  // ---- prologue: stage tile 0 -> buf0, tile 1 -> buf1 ----
#pragma unroll
  for (int j = 0; j < 4; ++j)
    __builtin_amdgcn_global_load_lds((gv_t*)(srcA + j * 524288), (lv_t*)(lds + j * 8192 + stgoff), 16, 0, 0);
#pragma unroll
  for (int j = 0; j < 4; ++j)
    __builtin_amdgcn_global_load_lds((gv_t*)(srcB + j * 524288), (lv_t*)(lds + 32768 + j * 8192 + stgoff), 16, 0, 0);
#pragma unroll
  for (int j = 0; j < 4; ++j)
    __builtin_amdgcn_global_load_lds((gv_t*)(srcA + 128 + j * 524288), (lv_t*)(lds + 65536 + j * 8192 + stgoff), 16, 0, 0);
#pragma unroll
  for (int j = 0; j < 4; ++j)
    __builtin_amdgcn_global_load_lds((gv_t*)(srcB + 128 + j * 524288), (lv_t*)(lds + 65536 + 32768 + j * 8192 + stgoff), 16, 0, 0);

  asm volatile("s_waitcnt vmcnt(8)" ::: "memory");   // tile 0 landed (tile 1 in flight)
  __builtin_amdgcn_sched_barrier(0);
  __builtin_amdgcn_s_barrier();
  __builtin_amdgcn_sched_barrier(0);

  bf16x8 aR[2][4], bR[2][4];
  // p0(0) operands from buf0
#pragma unroll
  for (int mi = 0; mi < 4; ++mi) aR[0][mi] = *(const bf16x8*)(lds + aoff0 + mi * 2048);
#pragma unroll
  for (int ni = 0; ni < 4; ++ni) bR[0][ni] = *(const bf16x8*)(lds + 32768 + boff0 + ni * 2048);

  for (int t = 0; t < NT; ++t) {
    const int cur = t & 1;
    char* Ac = lds + cur * 65536;
    char* Bc = Ac + 32768;
    char* An = lds + (cur ^ 1) * 65536;
    char* Bn = An + 32768;

    // ======== p0: MFMA (0,kh0); read A(1,kh0); stage tile t+1 ========
    if (t >= 1 && t + 1 < NT) {
      const long ko = (long)(t + 1) * 128;
#pragma unroll
      for (int j = 0; j < 4; ++j)
        __builtin_amdgcn_global_load_lds((gv_t*)(srcA + ko + j * 524288), (lv_t*)(An + j * 8192 + stgoff), 16, 0, 0);
#pragma unroll
      for (int j = 0; j < 4; ++j)
        __builtin_amdgcn_global_load_lds((gv_t*)(srcB + ko + j * 524288), (lv_t*)(Bn + j * 8192 + stgoff), 16, 0, 0);
    }
#pragma unroll
    for (int mi = 0; mi < 4; ++mi)
      aR[1][mi] = *(const bf16x8*)(Ac + (aoff0 + 8192) + mi * 2048);
    __builtin_amdgcn_s_setprio(1);
#pragma unroll
    for (int mi = 0; mi < 4; ++mi)
#pragma unroll
      for (int ni = 0; ni < 4; ++ni)
        acc[mi][ni] = __builtin_amdgcn_mfma_f32_16x16x32_bf16(aR[0][mi], bR[0][ni], acc[mi][ni], 0, 0, 0);
    __builtin_amdgcn_s_setprio(0);

    // ======== p1: MFMA (1,kh0); read A(0,kh1) + B(kh1) ========
#pragma unroll
    for (int mi = 0; mi < 4; ++mi)
      aR[0][mi] = *(const bf16x8*)(Ac + (aoff0 ^ 64) + mi * 2048);
#pragma unroll
    for (int ni = 0; ni < 4; ++ni)
      bR[1][ni] = *(const bf16x8*)(Bc + (boff0 ^ 64) + ni * 2048);
    __builtin_amdgcn_s_setprio(1);
#pragma unroll
    for (int mi = 0; mi < 4; ++mi)
#pragma unroll
      for (int ni = 0; ni < 4; ++ni)
        acc[4 + mi][ni] = __builtin_amdgcn_mfma_f32_16x16x32_bf16(aR[1][mi], bR[0][ni], acc[4 + mi][ni], 0, 0, 0);
    __builtin_amdgcn_s_setprio(0);

    // ======== p2: MFMA (0,kh1); read A(1,kh1); publish tile t+1 ========
#pragma unroll
    for (int mi = 0; mi < 4; ++mi)
      aR[1][mi] = *(const bf16x8*)(Ac + ((aoff0 + 8192) ^ 64) + mi * 2048);
    __builtin_amdgcn_s_setprio(1);
#pragma unroll
    for (int mi = 0; mi < 4; ++mi)
#pragma unroll
      for (int ni = 0; ni < 4; ++ni)
        acc[mi][ni] = __builtin_amdgcn_mfma_f32_16x16x32_bf16(aR[0][mi], bR[1][ni], acc[mi][ni], 0, 0, 0);
    __builtin_amdgcn_s_setprio(0);
    asm volatile("s_waitcnt vmcnt(0)" ::: "memory");   // t+1 loads issued 2 phases ago
    __builtin_amdgcn_sched_barrier(0);
    __builtin_amdgcn_s_barrier();                      // publish buf[t+1]
    __builtin_amdgcn_sched_barrier(0);

    // ======== p3: MFMA (1,kh1); read t+1 p0 operands ========
    if (t + 1 < NT) {
#pragma unroll
      for (int mi = 0; mi < 4; ++mi)
        aR[0][mi] = *(const bf16x8*)(An + aoff0 + mi * 2048);
#pragma unroll
      for (int ni = 0; ni < 4; ++ni)
        bR[0][ni] = *(const bf16x8*)(Bn + boff0 + ni * 2048);
    }
    __builtin_amdgcn_s_setprio(1);
#pragma unroll
    for (int mi = 0; mi < 4; ++mi)
#pragma unroll
      for (int ni = 0; ni < 4; ++ni)
        acc[4 + mi][ni] = __builtin_amdgcn_mfma_f32_16x16x32_bf16(aR[1][mi], bR[1][ni], acc[4 + mi][ni], 0, 0, 0);
    __builtin_amdgcn_s_setprio(0);
    __builtin_amdgcn_sched_barrier(0);
    __builtin_amdgcn_s_barrier();                      // protect buf[cur] for next staging
    __builtin_amdgcn_sched_barrier(0);
  }

  // ---- epilogue: C/D layout col=l&15, row=(l>>4)*4+reg ----
  const int row0 = by * 256 + wr * 128 + ((l >> 4) << 2);
  const int col0 = bx * 256 + wc * 64 + r4;
#pragma unroll
  for (int ni = 0; ni < 4; ++ni) {
    const int col = col0 + ni * 16;
    const float bv = bias[col];
#pragma unroll
    for (int mi = 0; mi < 8; ++mi) {
#pragma unroll
      for (int r = 0; r < 4; ++r)
        C[(size_t)(row0 + mi * 16 + r) * N_DIM + col] = acc[mi][ni][r] + bv;
    }
  }
}

// ---------------- fallback ----------------
__global__ void k_fallback(const float* __restrict__ x, const float* __restrict__ scales,
                           const float* __restrict__ bias, const int* __restrict__ w,
                           const int* __restrict__ ci, float* __restrict__ out) {
  const int n = blockIdx.x * 256 + threadIdx.x;
  const int m0 = blockIdx.y * 32;
  float acc[32];
#pragma unroll
  for (int i = 0; i < 32; ++i) acc[i] = 0.f;
  for (int k = 0; k < K_DIM; ++k) {
    int c = ci[k];
    float wv = (float)w[(long)k * N_DIM + n] * scales[(k >> 7) * N_DIM + n];
#pragma unroll 8
    for (int mm = 0; mm < 32; ++mm)
      acc[mm] += x[(long)(m0 + mm) * K_DIM + c] * wv;
  }
  float bv = bias[n];
  for (int mm = 0; mm < 32; ++mm)
    out[(long)(m0 + mm) * N_DIM + n] = acc[mm] + bv;
}

extern "C" void kernel_launch(void* const* d_in, const int* in_sizes, int n_in,
                              void* d_out, int out_size, void* d_ws, size_t ws_size,
                              hipStream_t stream) {
  const float* x      = (const float*)d_in[0];
  const float* scales = (const float*)d_in[1];
  const float* bias   = (const float*)d_in[2];
  const int*   wq     = (const int*)d_in[3];
  const int*   ci     = (const int*)d_in[4];
  float* out = (float*)d_out;

  const size_t xb_bytes  = (size_t)M_DIM * K_DIM * 2;
  const size_t w2t_bytes = (size_t)N_DIM * K_DIM * 2;
  const size_t need = xb_bytes + w2t_bytes + (size_t)K_DIM * 4;

  if (ws_size < need) {
    k_fallback<<<dim3(N_DIM / 256, M_DIM / 32), 256, 0, stream>>>(x, scales, bias, wq, ci, out);
    return;
  }

  unsigned short* xb  = (unsigned short*)d_ws;
  unsigned short* w2t = (unsigned short*)((char*)d_ws + xb_bytes);
  int* pinv           = (int*)((char*)d_ws + xb_bytes + w2t_bytes);

  k_pinv<<<K_DIM / 256, 256, 0, stream>>>(ci, pinv);
  k_cvt<<<2048, 256, 0, stream>>>(x, xb);
  k_w2t<<<dim3(N_DIM / 64, K_DIM / 64), 256, 0, stream>>>(wq, scales, pinv, w2t);
  k_gemm<<<(M_DIM / 256) * (N_DIM / 256), 512, 0, stream>>>(xb, w2t, bias, out);
}